// Round 1
// baseline (697.705 us; speedup 1.0000x reference)
//
#include <hip/hip_runtime.h>
#include <cstddef>

// Problem constants
constexpr int NTOK = 2048;   // B*S
constexpr int DIN  = 1024;
constexpr int DCF  = 64;     // compressed dim
constexpr int DBIG = 32768;  // D1 = D2
constexpr int KP   = 132;    // padded contraction dim: 128 (k*64+c) + 2 (bias rows) + 2 pad

// ---------------- prep: cf = tanh(x@Wc+bc); coeffs=softmax(cf@Wm+bm); f; ratio ----------------
__global__ __launch_bounds__(64) void prep_kernel(
    const float* __restrict__ x, const float* __restrict__ Wc, const float* __restrict__ bc,
    const float* __restrict__ Wm, const float* __restrict__ bm,
    const float* __restrict__ Wr, const float* __restrict__ br,
    float* __restrict__ f, float* __restrict__ cf_out, float* __restrict__ ratio)
{
  const int c  = threadIdx.x;       // 0..63
  const int t0 = blockIdx.x * 8;    // 8 tokens per block
  float s[8];
#pragma unroll
  for (int p = 0; p < 8; ++p) s[p] = bc[c];
  for (int j = 0; j < DIN; ++j) {
    float w = Wc[j * DCF + c];
#pragma unroll
    for (int p = 0; p < 8; ++p) s[p] = fmaf(x[(size_t)(t0 + p) * DIN + j], w, s[p]);
  }
#pragma unroll 1
  for (int p = 0; p < 8; ++p) {
    const int t = t0 + p;
    float cf = tanhf(s[p]);
    cf_out[(size_t)t * DCF + c] = cf;
    float z0 = cf * Wm[2 * c], z1 = cf * Wm[2 * c + 1], rr = cf * Wr[c];
    for (int off = 32; off; off >>= 1) {
      z0 += __shfl_down(z0, off);
      z1 += __shfl_down(z1, off);
      rr += __shfl_down(rr, off);
    }
    z0 = __shfl(z0, 0); z1 = __shfl(z1, 0); rr = __shfl(rr, 0);
    z0 += bm[0]; z1 += bm[1];
    float mx = fmaxf(z0, z1);
    float e0 = expf(z0 - mx), e1 = expf(z1 - mx);
    float a0 = e0 / (e0 + e1), a1 = 1.0f - a0;
    float* fr = f + (size_t)t * KP;
    fr[c]       = a0 * cf;
    fr[DCF + c] = a1 * cf;
    if (c == 0) {
      fr[128] = a0; fr[129] = a1; fr[130] = 0.f; fr[131] = 0.f;
      ratio[t] = rr + br[0];
    }
  }
}

// ---------------- bias = cf @ Wb + bb  [2048 x 1024] ----------------
__global__ __launch_bounds__(256) void bias_kernel(
    const float* __restrict__ cf, const float* __restrict__ Wb, const float* __restrict__ bb,
    float* __restrict__ bias)
{
  const int t0 = blockIdx.x * 8;
  const int n  = blockIdx.y * 256 + threadIdx.x;
  __shared__ float cfl[8][DCF];
  for (int idx = threadIdx.x; idx < 8 * DCF; idx += 256)
    cfl[idx / DCF][idx % DCF] = cf[(size_t)t0 * DCF + idx];
  __syncthreads();
  float s[8];
#pragma unroll
  for (int p = 0; p < 8; ++p) s[p] = 0.f;
  for (int c = 0; c < DCF; ++c) {
    float w = Wb[(size_t)c * 1024 + n];
#pragma unroll
    for (int p = 0; p < 8; ++p) s[p] = fmaf(cfl[p][c], w, s[p]);
  }
  float b = bb[n];
#pragma unroll
  for (int p = 0; p < 8; ++p) bias[(size_t)(t0 + p) * 1024 + n] = s[p] + b;
}

// ---------------- permute W into [KP][32768] with columns reordered (g,i,o)->(g,o,i) ----------
// Wp[j, g*1024 + o*32 + i] = W[j, g*1024 + i*32 + o];  rows 128/129 = biases, 130/131 = zero
__global__ __launch_bounds__(256) void perm_kernel(
    const float* __restrict__ W1, const float* __restrict__ b1,
    const float* __restrict__ W2, const float* __restrict__ b2,
    float* __restrict__ Wp1, float* __restrict__ Wp2)
{
  const int g = blockIdx.x;        // 0..31
  const int j = blockIdx.y;        // 0..131
  const int src = blockIdx.z;      // 0..1
  const float* Wsrc = src ? W2 : W1;
  const float* bsrc = src ? b2 : b1;
  float* dst = (src ? Wp2 : Wp1) + (size_t)j * DBIG + (size_t)g * 1024;
  const int tid = threadIdx.x;     // 256 threads, 4 floats each
  __shared__ float tile[32][33];
  if (j < 130) {
    const float* sp = (j < 128) ? Wsrc + (size_t)j * DBIG + (size_t)g * 1024
                                : bsrc + (size_t)(j - 128) * DBIG + (size_t)g * 1024;
    float4 v = reinterpret_cast<const float4*>(sp)[tid];
    int e = tid * 4;
    int i = e >> 5, o = e & 31;    // e = i*32 + o
    tile[i][o] = v.x; tile[i][o + 1] = v.y; tile[i][o + 2] = v.z; tile[i][o + 3] = v.w;
    __syncthreads();
    int e2 = tid * 4;
    int oo = e2 >> 5, ii = e2 & 31; // e2 = oo*32 + ii
    float4 w;
    w.x = tile[ii][oo]; w.y = tile[ii + 1][oo]; w.z = tile[ii + 2][oo]; w.w = tile[ii + 3][oo];
    reinterpret_cast<float4*>(dst)[tid] = w;
  } else {
    float4 z = {0.f, 0.f, 0.f, 0.f};
    reinterpret_cast<float4*>(dst)[tid] = z;
  }
}

// ---------------- main GEMM + fused monarch-block reduction ----------------
// C[t, n'] = sum_j f[t,j] * Wp[j, n'],  n' = g*1024 + o*32 + i
// PASS 1: h1[t, g*32+o] = sum_i x[t, g*32+i]        * C[t, g*1024+o*32+i]
// PASS 2: out[t, g*32+o] = (sum_i h1[t, i*32+g] * C[t, ...]) * ratio[t] + bias[t, g*32+o]
template <int PASS>
__global__ __launch_bounds__(256) void gemm_kernel(
    const float* __restrict__ f,    // [2048][KP]
    const float* __restrict__ Wp,   // [KP][32768]
    const float* __restrict__ xin,  // pass1: x [2048][1024]; pass2: h1 [2048][1024]
    const float* __restrict__ ratio,
    const float* __restrict__ bias,
    float* __restrict__ outp)       // pass1: h1; pass2: out
{
  constexpr int KC = 6;   // k-chunk
  constexpr int NT = 256; // cols per block
  constexpr int TT = 64;  // tokens per block
  __shared__ float f_lds[TT * KP];       // [t][k]
  __shared__ float w_lds[KC][NT];
  __shared__ float x_lds[TT][33];
  __shared__ float r_lds[TT];

  const int tid = threadIdx.x;
  const int tx = tid & 31, ty = tid >> 5;
  const int n0 = blockIdx.x * NT;
  const int t0 = blockIdx.y * TT;

  for (int idx = tid; idx < TT * KP; idx += 256)
    f_lds[idx] = f[(size_t)t0 * KP + idx];

  float acc[8][8];
#pragma unroll
  for (int r = 0; r < 8; ++r)
#pragma unroll
    for (int j = 0; j < 8; ++j) acc[r][j] = 0.f;

  for (int kc = 0; kc < KP; kc += KC) {
    __syncthreads();
#pragma unroll
    for (int r = 0; r < KC; ++r)
      w_lds[r][tid] = Wp[(size_t)(kc + r) * DBIG + n0 + tid];
    __syncthreads();
#pragma unroll
    for (int k = 0; k < KC; ++k) {
      float wv[8];
#pragma unroll
      for (int j = 0; j < 8; ++j) wv[j] = w_lds[k][tx * 8 + j];
#pragma unroll
      for (int r = 0; r < 8; ++r) {
        float m = f_lds[(ty * 8 + r) * KP + kc + k];
#pragma unroll
        for (int j = 0; j < 8; ++j) acc[r][j] = fmaf(m, wv[j], acc[r][j]);
      }
    }
  }

  // stage per-token multiplier vectors for this g-block
  const int g = n0 >> 10;
  __syncthreads();
  for (int idx = tid; idx < TT * 32; idx += 256) {
    int t = idx >> 5, i = idx & 31;
    float v;
    if (PASS == 1) v = xin[(size_t)(t0 + t) * 1024 + g * 32 + i];
    else           v = xin[(size_t)(t0 + t) * 1024 + i * 32 + g];
    x_lds[t][i] = v;
  }
  if (PASS == 2 && tid < TT) r_lds[tid] = ratio[t0 + tid];
  __syncthreads();

  const int ib   = (tx & 3) * 8;              // i-offset within the 32-run
  const int orun = tx >> 2;                   // 0..7 runs in this tile
  const int og   = ((n0 & 1023) >> 5) + orun; // output o
#pragma unroll
  for (int r = 0; r < 8; ++r) {
    int t = ty * 8 + r;
    float s = 0.f;
#pragma unroll
    for (int j = 0; j < 8; ++j) s += acc[r][j] * x_lds[t][ib + j];
    s += __shfl_down(s, 2, 4);
    s += __shfl_down(s, 1, 4);
    if ((tx & 3) == 0) {
      size_t oidx = (size_t)(t0 + t) * 1024 + g * 32 + og;
      if (PASS == 1) outp[oidx] = s;
      else           outp[oidx] = s * r_lds[t] + bias[oidx];
    }
  }
}

extern "C" void kernel_launch(void* const* d_in, const int* in_sizes, int n_in,
                              void* d_out, int out_size, void* d_ws, size_t ws_size,
                              hipStream_t stream) {
  const float* x  = (const float*)d_in[0];
  const float* Wc = (const float*)d_in[1];
  const float* bc = (const float*)d_in[2];
  const float* W1 = (const float*)d_in[3];
  const float* b1 = (const float*)d_in[4];
  const float* W2 = (const float*)d_in[5];
  const float* b2 = (const float*)d_in[6];
  const float* Wm = (const float*)d_in[7];
  const float* bm = (const float*)d_in[8];
  const float* Wb = (const float*)d_in[9];
  const float* bb = (const float*)d_in[10];
  const float* Wr = (const float*)d_in[11];
  const float* br = (const float*)d_in[12];
  float* out = (float*)d_out;

  float* ws    = (float*)d_ws;
  float* Wp1   = ws;                                   // 132*32768
  float* Wp2   = Wp1 + (size_t)KP * DBIG;              // 132*32768
  float* f     = Wp2 + (size_t)KP * DBIG;              // 2048*132
  float* cf    = f + (size_t)NTOK * KP;                // 2048*64
  float* ratio = cf + (size_t)NTOK * DCF;              // 2048
  float* h1    = ratio + NTOK;                         // 2048*1024
  float* bias  = h1 + (size_t)NTOK * 1024;             // 2048*1024

  prep_kernel<<<dim3(NTOK / 8), dim3(64), 0, stream>>>(x, Wc, bc, Wm, bm, Wr, br, f, cf, ratio);
  bias_kernel<<<dim3(NTOK / 8, 4), dim3(256), 0, stream>>>(cf, Wb, bb, bias);
  perm_kernel<<<dim3(32, KP, 2), dim3(256), 0, stream>>>(W1, b1, W2, b2, Wp1, Wp2);
  gemm_kernel<1><<<dim3(DBIG / 256, NTOK / 64), dim3(256), 0, stream>>>(f, Wp1, x, nullptr, nullptr, h1);
  gemm_kernel<2><<<dim3(DBIG / 256, NTOK / 64), dim3(256), 0, stream>>>(f, Wp2, h1, ratio, bias, out);
}

// Round 3
// 154.890 us; speedup vs baseline: 4.5045x; 4.5045x over previous
//
#include <hip/hip_runtime.h>
#include <cstddef>

typedef unsigned short ushortT;
typedef short s8v __attribute__((ext_vector_type(8)));
typedef float f32x4 __attribute__((ext_vector_type(4)));

constexpr int NTOK = 2048;   // B*S
constexpr int DBIG = 32768;  // D1 = D2
constexpr int KPAD = 160;    // padded contraction: 128 (k*64+c) + 2 bias + 30 zero
// packed tile: 16 cols x 160 k = 5 ks-steps x 512 elems = 2560 elems

__device__ inline ushortT f2bf(float f) {
  unsigned u = __float_as_uint(f);
  u += 0x7fffu + ((u >> 16) & 1u);
  return (ushortT)(u >> 16);
}

// ---------------- prep: cf, softmax coeffs, ratio, packed-f fragments ----------------
__global__ __launch_bounds__(256) void prep_kernel(
    const float* __restrict__ x, const float* __restrict__ Wc, const float* __restrict__ bc,
    const float* __restrict__ Wm, const float* __restrict__ bm,
    const float* __restrict__ Wr, const float* __restrict__ br,
    ushortT* __restrict__ FP, float* __restrict__ cf_out, float* __restrict__ ratio)
{
  const int tid = threadIdx.x;
  const int c  = tid & 63;     // channel
  const int wv = tid >> 6;     // wave: tokens wv*4..+3 of this tile
  const int tt = blockIdx.x;   // token tile (16 tokens)
  const int tbase = tt * 16 + wv * 4;
  __shared__ float a0s[16], a1s[16];

  float s[4];
#pragma unroll
  for (int p = 0; p < 4; ++p) s[p] = bc[c];
  for (int j = 0; j < 1024; ++j) {
    float w = Wc[j * 64 + c];
#pragma unroll
    for (int p = 0; p < 4; ++p)
      s[p] = fmaf(x[(size_t)(tbase + p) * 1024 + j], w, s[p]);
  }
  float cfr[4];
#pragma unroll
  for (int p = 0; p < 4; ++p) {
    cfr[p] = tanhf(s[p]);
    cf_out[(size_t)(tbase + p) * 64 + c] = cfr[p];
  }
#pragma unroll 1
  for (int p = 0; p < 4; ++p) {
    float z0 = cfr[p] * Wm[2 * c], z1 = cfr[p] * Wm[2 * c + 1], rr = cfr[p] * Wr[c];
    for (int off = 32; off; off >>= 1) {
      z0 += __shfl_down(z0, off);
      z1 += __shfl_down(z1, off);
      rr += __shfl_down(rr, off);
    }
    if (c == 0) {
      z0 += bm[0]; z1 += bm[1];
      float mx = fmaxf(z0, z1);
      float e0 = expf(z0 - mx), e1 = expf(z1 - mx);
      float a0 = e0 / (e0 + e1);
      a0s[wv * 4 + p] = a0;
      a1s[wv * 4 + p] = 1.0f - a0;
      ratio[tbase + p] = rr + br[0];
    }
  }
  __syncthreads();
  // pack f fragments: elem = tt*2560 + ks*512 + ((kk>>3)*16 + tok)*8 + (kk&7)
  const size_t base = (size_t)tt * 2560;
  const int ks0 = c >> 5, kk = c & 31;
  const int slot = (kk >> 3) * 16, e = kk & 7;
#pragma unroll
  for (int p = 0; p < 4; ++p) {
    int tok = wv * 4 + p;
    float a0 = a0s[tok], a1 = a1s[tok];
    FP[base + (size_t)ks0 * 512 + (slot + tok) * 8 + e]       = f2bf(a0 * cfr[p]);
    FP[base + (size_t)(2 + ks0) * 512 + (slot + tok) * 8 + e] = f2bf(a1 * cfr[p]);
  }
  if (c < 32) {
#pragma unroll
    for (int p = 0; p < 4; ++p) {
      int tok = wv * 4 + p;
      float v = (c == 0) ? a0s[tok] : (c == 1) ? a1s[tok] : 0.0f;
      FP[base + 4 * 512 + ((c >> 3) * 16 + tok) * 8 + (c & 7)] = f2bf(v);
    }
  }
}

// ---------------- bias = cf @ Wb + bb  [2048 x 1024] ----------------
__global__ __launch_bounds__(256) void bias_kernel(
    const float* __restrict__ cf, const float* __restrict__ Wb, const float* __restrict__ bb,
    float* __restrict__ bias)
{
  const int t0 = blockIdx.x * 8;
  const int n  = blockIdx.y * 256 + threadIdx.x;
  __shared__ float cfl[8][64];
  for (int idx = threadIdx.x; idx < 8 * 64; idx += 256)
    cfl[idx / 64][idx % 64] = cf[(size_t)t0 * 64 + idx];
  __syncthreads();
  float s[8];
#pragma unroll
  for (int p = 0; p < 8; ++p) s[p] = 0.f;
  for (int c = 0; c < 64; ++c) {
    float w = Wb[(size_t)c * 1024 + n];
#pragma unroll
    for (int p = 0; p < 8; ++p) s[p] = fmaf(cfl[p][c], w, s[p]);
  }
  float b = bb[n];
#pragma unroll
  for (int p = 0; p < 8; ++p) bias[(size_t)(t0 + p) * 1024 + n] = s[p] + b;
}

// ---------------- pack W: permute (g,i,o)->(g,o,i), bf16, fragment-major ----------------
// out elem = ct*2560 + ks*512 + ((kk>>3)*16 + cl)*8 + (kk&7), col c = ct*16+cl = g*1024+o*32+i
__global__ __launch_bounds__(256) void pack_w_kernel(
    const float* __restrict__ W1, const float* __restrict__ b1,
    const float* __restrict__ W2, const float* __restrict__ b2,
    ushortT* __restrict__ P1, ushortT* __restrict__ P2)
{
  const int g = blockIdx.x, jc = blockIdx.y, fac = blockIdx.z;
  const float* W  = fac ? W2 : W1;
  const float* bv = fac ? b2 : b1;
  ushortT* P = fac ? P2 : P1;
  const int tid = threadIdx.x;
  __shared__ ushortT lds[16][1024];

  // FIX (round 2 NaN): 16 rows x 256 float4 = 4096 groups -> 16 iterations, not 4.
#pragma unroll
  for (int it = 0; it < 16; ++it) {
    int idx = tid + it * 256;
    int rl = idx >> 8, c4 = idx & 255;
    int jj = jc * 16 + rl;
    float4 v = make_float4(0.f, 0.f, 0.f, 0.f);
    if (jj < 128)       v = *(const float4*)(W  + (size_t)jj * 32768 + g * 1024 + c4 * 4);
    else if (jj < 130)  v = *(const float4*)(bv + (size_t)(jj - 128) * 32768 + g * 1024 + c4 * 4);
    ushortT* d = &lds[rl][c4 * 4];
    d[0] = f2bf(v.x); d[1] = f2bf(v.y); d[2] = f2bf(v.z); d[3] = f2bf(v.w);
  }
  __syncthreads();
  const int ks = jc >> 1, kh = jc & 1;
#pragma unroll
  for (int it = 0; it < 8; ++it) {
    int idx = tid + it * 256;          // 2048: ct_l(64) x kkg_l(2) x cl(16)
    int ct_l = idx >> 5, kkg_l = (idx >> 4) & 1, cl = idx & 15;
    int o = ct_l >> 1, ib = (ct_l & 1) * 16;
    int scol = (ib + cl) * 32 + o;
    int r0 = kkg_l * 8;
    ushortT v[8];
#pragma unroll
    for (int e = 0; e < 8; ++e) v[e] = lds[r0 + e][scol];
    int kkg = kh * 2 + kkg_l;
    size_t off = (size_t)(g * 64 + ct_l) * 2560 + (size_t)ks * 512 + (kkg * 16 + cl) * 8;
    uint4 q;
    q.x = v[0] | ((unsigned)v[1] << 16);
    q.y = v[2] | ((unsigned)v[3] << 16);
    q.z = v[4] | ((unsigned)v[5] << 16);
    q.w = v[6] | ((unsigned)v[7] << 16);
    *(uint4*)(P + off) = q;
  }
}

// ---------------- transpose h1 [t][i*32+g] -> h1x [g][t][i] ----------------
__global__ __launch_bounds__(256) void tr_kernel(
    const float* __restrict__ h1, float* __restrict__ h1x)
{
  __shared__ float lds[8 * 1061];
  const int tid = threadIdx.x, t0 = blockIdx.x * 8;
#pragma unroll
  for (int it = 0; it < 8; ++it) {
    int idx = tid + it * 256;          // 2048: 8 rows x 256 float4
    int r = idx >> 8, c4 = idx & 255;
    float4 v = *(const float4*)(h1 + (size_t)(t0 + r) * 1024 + c4 * 4);
    int cc = c4 * 4, i = cc >> 5, b0 = cc & 31;
    float* d = lds + r * 1061 + i * 33 + b0;
    d[0] = v.x; d[1] = v.y; d[2] = v.z; d[3] = v.w;
  }
  __syncthreads();
#pragma unroll
  for (int it = 0; it < 8; ++it) {
    int idx = tid + it * 256;          // 2048: g(32) x r(8) x i4(8)
    int g = idx >> 6, rest = idx & 63, r = rest >> 3, i4 = rest & 7;
    float4 v;
    v.x = lds[r * 1061 + (i4 * 4 + 0) * 33 + g];
    v.y = lds[r * 1061 + (i4 * 4 + 1) * 33 + g];
    v.z = lds[r * 1061 + (i4 * 4 + 2) * 33 + g];
    v.w = lds[r * 1061 + (i4 * 4 + 3) * 33 + g];
    *(float4*)(h1x + (size_t)g * 65536 + (size_t)(t0 + r) * 32 + i4 * 4) = v;
  }
}

// ---------------- MFMA GEMM + fused monarch reduction ----------------
// M = packed W cols (i fastest), N = tokens. D tile per wave: 64 cols x 64 tokens.
template <int PASS>
__global__ __launch_bounds__(256) void mm_kernel(
    const s8v* __restrict__ fP, const s8v* __restrict__ wP,
    const float* __restrict__ xg,    // pass1: x; pass2: h1x
    const float* __restrict__ rat, const float* __restrict__ bias,
    float* __restrict__ outp)        // pass1: h1; pass2: out
{
  __shared__ float xs[64][33];
  __shared__ float hs[64][9];
  const int tid = threadIdx.x;
  const int lane = tid & 63;
  const int w = tid >> 6;
  const int cb = blockIdx.x;   // 0..127: 256-col block
  const int tb = blockIdx.y;   // 0..31: 64-token block
  const int g = cb >> 2;
  const int t0 = tb * 64;

  f32x4 acc[4][4];
#pragma unroll
  for (int i = 0; i < 4; ++i)
#pragma unroll
    for (int j = 0; j < 4; ++j) acc[i][j] = {0.f, 0.f, 0.f, 0.f};

  const s8v* ap = wP + (size_t)(cb * 16 + w * 4) * 320 + lane;
  const s8v* bp = fP + (size_t)(tb * 4) * 320 + lane;

#pragma unroll
  for (int ks = 0; ks < 5; ++ks) {
    s8v a[4], b[4];
#pragma unroll
    for (int i = 0; i < 4; ++i) a[i] = ap[i * 320 + ks * 64];
#pragma unroll
    for (int j = 0; j < 4; ++j) b[j] = bp[j * 320 + ks * 64];
#pragma unroll
    for (int i = 0; i < 4; ++i)
#pragma unroll
      for (int j = 0; j < 4; ++j)
        acc[i][j] = __builtin_amdgcn_mfma_f32_16x16x32_bf16(a[i], b[j], acc[i][j], 0, 0, 0);
  }

  // stage multiplier vectors xv[t, i] for this g
#pragma unroll
  for (int it = 0; it < 2; ++it) {
    int idx = tid + it * 256;          // 512: 64 t x 8 i4
    int t = idx >> 3, i4 = idx & 7;
    float4 v;
    if (PASS == 1) v = *(const float4*)(xg + (size_t)(t0 + t) * 1024 + g * 32 + i4 * 4);
    else           v = *(const float4*)(xg + (size_t)g * 65536 + (size_t)(t0 + t) * 32 + i4 * 4);
    float* d = &xs[t][i4 * 4];
    d[0] = v.x; d[1] = v.y; d[2] = v.z; d[3] = v.w;
  }
  __syncthreads();

  const int tau = lane & 15, q = lane >> 4;
#pragma unroll
  for (int tt = 0; tt < 4; ++tt) {
    int tl = tt * 16 + tau;
#pragma unroll
    for (int run = 0; run < 2; ++run) {
      float sacc = 0.f;
#pragma unroll
      for (int ch = 0; ch < 2; ++ch) {
        int ct = run * 2 + ch;
        const float* xv = &xs[tl][ch * 16 + q * 4];
        f32x4 av = acc[ct][tt];
        sacc += av[0] * xv[0] + av[1] * xv[1] + av[2] * xv[2] + av[3] * xv[3];
      }
      sacc += __shfl_xor(sacc, 16);
      sacc += __shfl_xor(sacc, 32);
      if (lane < 16) hs[tl][w * 2 + run] = sacc;
    }
  }
  __syncthreads();

  if (tid < 128) {
    int row = tid >> 1, half = tid & 1;
    int t = t0 + row;
    int col = g * 32 + (cb & 3) * 8 + half * 4;
    float v0 = hs[row][half * 4 + 0], v1 = hs[row][half * 4 + 1];
    float v2 = hs[row][half * 4 + 2], v3 = hs[row][half * 4 + 3];
    float4 o;
    if (PASS == 2) {
      float r = rat[t];
      float4 bv = *(const float4*)(bias + (size_t)t * 1024 + col);
      o.x = fmaf(v0, r, bv.x); o.y = fmaf(v1, r, bv.y);
      o.z = fmaf(v2, r, bv.z); o.w = fmaf(v3, r, bv.w);
    } else {
      o.x = v0; o.y = v1; o.z = v2; o.w = v3;
    }
    *(float4*)(outp + (size_t)t * 1024 + col) = o;
  }
}

extern "C" void kernel_launch(void* const* d_in, const int* in_sizes, int n_in,
                              void* d_out, int out_size, void* d_ws, size_t ws_size,
                              hipStream_t stream) {
  const float* x  = (const float*)d_in[0];
  const float* Wc = (const float*)d_in[1];
  const float* bc = (const float*)d_in[2];
  const float* W1 = (const float*)d_in[3];
  const float* b1 = (const float*)d_in[4];
  const float* W2 = (const float*)d_in[5];
  const float* b2 = (const float*)d_in[6];
  const float* Wm = (const float*)d_in[7];
  const float* bm = (const float*)d_in[8];
  const float* Wb = (const float*)d_in[9];
  const float* bb = (const float*)d_in[10];
  const float* Wr = (const float*)d_in[11];
  const float* br = (const float*)d_in[12];
  float* out = (float*)d_out;

  // workspace carve-up (bf16 packs first, then fp32 buffers)
  ushortT* P1 = (ushortT*)d_ws;                         // 2048*2560 bf16
  ushortT* P2 = P1 + (size_t)2048 * 2560;               // 2048*2560 bf16
  ushortT* FP = P2 + (size_t)2048 * 2560;               // 128*2560 bf16
  float* cf    = (float*)(FP + (size_t)128 * 2560);     // 2048*64
  float* ratio = cf + (size_t)NTOK * 64;                // 2048
  float* h1    = ratio + NTOK;                          // 2048*1024
  float* h1x   = h1 + (size_t)NTOK * 1024;              // 32*2048*32
  float* bias  = h1x + (size_t)NTOK * 1024;             // 2048*1024

  prep_kernel<<<dim3(128), dim3(256), 0, stream>>>(x, Wc, bc, Wm, bm, Wr, br, FP, cf, ratio);
  bias_kernel<<<dim3(256, 4), dim3(256), 0, stream>>>(cf, Wb, bb, bias);
  pack_w_kernel<<<dim3(32, 10, 2), dim3(256), 0, stream>>>(W1, b1, W2, b2, P1, P2);
  mm_kernel<1><<<dim3(128, 32), dim3(256), 0, stream>>>(
      (const s8v*)FP, (const s8v*)P1, x, nullptr, nullptr, h1);
  tr_kernel<<<dim3(256), dim3(256), 0, stream>>>(h1, h1x);
  mm_kernel<2><<<dim3(128, 32), dim3(256), 0, stream>>>(
      (const s8v*)FP, (const s8v*)P2, h1x, ratio, bias, out);
}

// Round 4
// 124.828 us; speedup vs baseline: 5.5893x; 1.2408x over previous
//
#include <hip/hip_runtime.h>
#include <cstddef>

typedef unsigned short ushortT;
typedef short s8v __attribute__((ext_vector_type(8)));
typedef float f32x4 __attribute__((ext_vector_type(4)));

constexpr int NTOK = 2048;   // B*S
constexpr int DBIG = 32768;  // D1 = D2
constexpr int KPAD = 160;    // padded contraction: 128 (k*64+c) + 2 bias + 30 zero
// packed tile: 16 cols x 160 k = 5 ks-steps x 512 elems = 2560 elems

__device__ inline ushortT f2bf(float f) {
  unsigned u = __float_as_uint(f);
  u += 0x7fffu + ((u >> 16) & 1u);
  return (ushortT)(u >> 16);
}

// ---------------- prep: cf, softmax coeffs, ratio, packed-f fragments ----------------
// 256 blocks x 8 tokens. j-dim split across 4 waves; float4-vectorized; LDS reduce.
__global__ __launch_bounds__(256) void prep_kernel(
    const float* __restrict__ x, const float* __restrict__ Wc, const float* __restrict__ bc,
    const float* __restrict__ Wm, const float* __restrict__ bm,
    const float* __restrict__ Wr, const float* __restrict__ br,
    ushortT* __restrict__ FP, float* __restrict__ cf_out, float* __restrict__ ratio)
{
  const int tid = threadIdx.x;
  const int c = tid & 63;      // channel
  const int q = tid >> 6;      // j-quarter (wave id)
  const int t0 = blockIdx.x * 8;
  __shared__ float part[4][8][64];
  __shared__ float cf_s[8][64];
  __shared__ float a0s[8], a1s[8];

  float acc[8];
#pragma unroll
  for (int p = 0; p < 8; ++p) acc[p] = 0.f;

  const float* xq = x + (size_t)t0 * 1024 + q * 256;
  const float* wq = Wc + (size_t)(q * 256) * 64 + c;
#pragma unroll 4
  for (int jj = 0; jj < 64; ++jj) {
    float w0 = wq[(jj * 4 + 0) * 64];
    float w1 = wq[(jj * 4 + 1) * 64];
    float w2 = wq[(jj * 4 + 2) * 64];
    float w3 = wq[(jj * 4 + 3) * 64];
#pragma unroll
    for (int p = 0; p < 8; ++p) {
      float4 xv = *(const float4*)(xq + (size_t)p * 1024 + jj * 4);
      acc[p] = fmaf(xv.x, w0, acc[p]);
      acc[p] = fmaf(xv.y, w1, acc[p]);
      acc[p] = fmaf(xv.z, w2, acc[p]);
      acc[p] = fmaf(xv.w, w3, acc[p]);
    }
  }
#pragma unroll
  for (int p = 0; p < 8; ++p) part[q][p][c] = acc[p];
  __syncthreads();

#pragma unroll
  for (int r = 0; r < 2; ++r) {
    int idx = tid + r * 256;
    int p = idx >> 6, cc = idx & 63;
    float s = part[0][p][cc] + part[1][p][cc] + part[2][p][cc] + part[3][p][cc] + bc[cc];
    float cf = tanhf(s);
    cf_s[p][cc] = cf;
    cf_out[(size_t)(t0 + p) * 64 + cc] = cf;
  }
  __syncthreads();

  // softmax + ratio: wave q handles tokens q*2, q*2+1
#pragma unroll 1
  for (int pp = 0; pp < 2; ++pp) {
    int p = q * 2 + pp;
    float cf = cf_s[p][c];
    float z0 = cf * Wm[2 * c], z1 = cf * Wm[2 * c + 1], rr = cf * Wr[c];
    for (int off = 32; off; off >>= 1) {
      z0 += __shfl_down(z0, off);
      z1 += __shfl_down(z1, off);
      rr += __shfl_down(rr, off);
    }
    if (c == 0) {
      z0 += bm[0]; z1 += bm[1];
      float mx = fmaxf(z0, z1);
      float e0 = expf(z0 - mx), e1 = expf(z1 - mx);
      float a0 = e0 / (e0 + e1);
      a0s[p] = a0;
      a1s[p] = 1.0f - a0;
      ratio[t0 + p] = rr + br[0];
    }
  }
  __syncthreads();

  // pack f fragments: elem = tt*2560 + ks*512 + ((kk>>3)*16 + tok)*8 + (kk&7)
  const int ks0 = c >> 5, kk = c & 31;
  const int slot = (kk >> 3) * 16, e = kk & 7;
#pragma unroll
  for (int pp = 0; pp < 2; ++pp) {
    int p = q * 2 + pp;
    int t = t0 + p, tt = t >> 4, tok = t & 15;
    size_t base = (size_t)tt * 2560;
    float cf = cf_s[p][c];
    float a0 = a0s[p], a1 = a1s[p];
    FP[base + (size_t)ks0 * 512 + (slot + tok) * 8 + e]       = f2bf(a0 * cf);
    FP[base + (size_t)(2 + ks0) * 512 + (slot + tok) * 8 + e] = f2bf(a1 * cf);
    if (c < 32) {
      float v = (c == 0) ? a0 : (c == 1) ? a1 : 0.0f;
      FP[base + 4 * 512 + ((c >> 3) * 16 + tok) * 8 + (c & 7)] = f2bf(v);
    }
  }
}

// ---------------- bias = cf @ Wb + bb  [2048 x 1024] ----------------
__global__ __launch_bounds__(256) void bias_kernel(
    const float* __restrict__ cf, const float* __restrict__ Wb, const float* __restrict__ bb,
    float* __restrict__ bias)
{
  const int t0 = blockIdx.x * 8;
  const int n  = blockIdx.y * 256 + threadIdx.x;
  __shared__ float cfl[8][64];
  for (int idx = threadIdx.x; idx < 8 * 64; idx += 256)
    cfl[idx / 64][idx % 64] = cf[(size_t)t0 * 64 + idx];
  __syncthreads();
  float s[8];
#pragma unroll
  for (int p = 0; p < 8; ++p) s[p] = 0.f;
  for (int c = 0; c < 64; ++c) {
    float w = Wb[(size_t)c * 1024 + n];
#pragma unroll
    for (int p = 0; p < 8; ++p) s[p] = fmaf(cfl[p][c], w, s[p]);
  }
  float b = bb[n];
#pragma unroll
  for (int p = 0; p < 8; ++p) bias[(size_t)(t0 + p) * 1024 + n] = s[p] + b;
}

// ---------------- pack W: permute (g,i,o)->(g,o,i), bf16, fragment-major ----------------
// out elem = ct*2560 + ks*512 + ((kk>>3)*16 + cl)*8 + (kk&7), col c = ct*16+cl = g*1024+o*32+i
__global__ __launch_bounds__(256) void pack_w_kernel(
    const float* __restrict__ W1, const float* __restrict__ b1,
    const float* __restrict__ W2, const float* __restrict__ b2,
    ushortT* __restrict__ P1, ushortT* __restrict__ P2)
{
  const int g = blockIdx.x, jc = blockIdx.y, fac = blockIdx.z;
  const float* W  = fac ? W2 : W1;
  const float* bv = fac ? b2 : b1;
  ushortT* P = fac ? P2 : P1;
  const int tid = threadIdx.x;
  __shared__ ushortT lds[16][1024];

#pragma unroll
  for (int it = 0; it < 16; ++it) {
    int idx = tid + it * 256;
    int rl = idx >> 8, c4 = idx & 255;
    int jj = jc * 16 + rl;
    float4 v = make_float4(0.f, 0.f, 0.f, 0.f);
    if (jj < 128)       v = *(const float4*)(W  + (size_t)jj * 32768 + g * 1024 + c4 * 4);
    else if (jj < 130)  v = *(const float4*)(bv + (size_t)(jj - 128) * 32768 + g * 1024 + c4 * 4);
    ushortT* d = &lds[rl][c4 * 4];
    d[0] = f2bf(v.x); d[1] = f2bf(v.y); d[2] = f2bf(v.z); d[3] = f2bf(v.w);
  }
  __syncthreads();
  const int ks = jc >> 1, kh = jc & 1;
#pragma unroll
  for (int it = 0; it < 8; ++it) {
    int idx = tid + it * 256;          // 2048: ct_l(64) x kkg_l(2) x cl(16)
    int ct_l = idx >> 5, kkg_l = (idx >> 4) & 1, cl = idx & 15;
    int o = ct_l >> 1, ib = (ct_l & 1) * 16;
    int scol = (ib + cl) * 32 + o;
    int r0 = kkg_l * 8;
    ushortT v[8];
#pragma unroll
    for (int e = 0; e < 8; ++e) v[e] = lds[r0 + e][scol];
    int kkg = kh * 2 + kkg_l;
    size_t off = (size_t)(g * 64 + ct_l) * 2560 + (size_t)ks * 512 + (kkg * 16 + cl) * 8;
    uint4 q;
    q.x = v[0] | ((unsigned)v[1] << 16);
    q.y = v[2] | ((unsigned)v[3] << 16);
    q.z = v[4] | ((unsigned)v[5] << 16);
    q.w = v[6] | ((unsigned)v[7] << 16);
    *(uint4*)(P + off) = q;
  }
}

// ---------------- transpose h1 [t][i*32+g] -> h1x [g][t][i] ----------------
__global__ __launch_bounds__(256) void tr_kernel(
    const float* __restrict__ h1, float* __restrict__ h1x)
{
  __shared__ float lds[8 * 1061];
  const int tid = threadIdx.x, t0 = blockIdx.x * 8;
#pragma unroll
  for (int it = 0; it < 8; ++it) {
    int idx = tid + it * 256;          // 2048: 8 rows x 256 float4
    int r = idx >> 8, c4 = idx & 255;
    float4 v = *(const float4*)(h1 + (size_t)(t0 + r) * 1024 + c4 * 4);
    int cc = c4 * 4, i = cc >> 5, b0 = cc & 31;
    float* d = lds + r * 1061 + i * 33 + b0;
    d[0] = v.x; d[1] = v.y; d[2] = v.z; d[3] = v.w;
  }
  __syncthreads();
#pragma unroll
  for (int it = 0; it < 8; ++it) {
    int idx = tid + it * 256;          // 2048: g(32) x r(8) x i4(8)
    int g = idx >> 6, rest = idx & 63, r = rest >> 3, i4 = rest & 7;
    float4 v;
    v.x = lds[r * 1061 + (i4 * 4 + 0) * 33 + g];
    v.y = lds[r * 1061 + (i4 * 4 + 1) * 33 + g];
    v.z = lds[r * 1061 + (i4 * 4 + 2) * 33 + g];
    v.w = lds[r * 1061 + (i4 * 4 + 3) * 33 + g];
    *(float4*)(h1x + (size_t)g * 65536 + (size_t)(t0 + r) * 32 + i4 * 4) = v;
  }
}

// ---------------- MFMA GEMM + fused monarch reduction ----------------
// A-frags (P cols) held in registers across 4 token-tiles; XCD-swizzled bid so the
// 8 blocks sharing a cb land on one XCD (P slice 1.3MB + FP 640KB fit 4MB L2).
template <int PASS>
__global__ __launch_bounds__(256, 2) void mm_kernel(
    const s8v* __restrict__ fP, const s8v* __restrict__ wP,
    const float* __restrict__ xg,    // pass1: x; pass2: h1x
    const float* __restrict__ rat, const float* __restrict__ bias,
    float* __restrict__ outp)        // pass1: h1; pass2: out
{
  __shared__ float xs[64][33];
  __shared__ float hs[64][9];
  const int tid = threadIdx.x;
  const int lane = tid & 63;
  const int w = tid >> 6;
  const int bid = blockIdx.x;                 // 0..1023
  const int cb  = (bid & 7) * 16 + (bid >> 6);  // 0..127
  const int tbg = (bid >> 3) & 7;               // 0..7
  const int g = cb >> 2;

  // load A fragments once (16 col-tiles per block, 4 per wave, 5 ks each)
  const s8v* ap = wP + (size_t)(cb * 16 + w * 4) * 320 + lane;
  s8v a[4][5];
#pragma unroll
  for (int i = 0; i < 4; ++i)
#pragma unroll
    for (int ks = 0; ks < 5; ++ks) a[i][ks] = ap[i * 320 + ks * 64];

#pragma unroll 1
  for (int tt2 = 0; tt2 < 4; ++tt2) {
    const int tb = tbg * 4 + tt2;
    const int t0 = tb * 64;

    f32x4 acc[4][4];
#pragma unroll
    for (int i = 0; i < 4; ++i)
#pragma unroll
      for (int j = 0; j < 4; ++j) acc[i][j] = {0.f, 0.f, 0.f, 0.f};

    const s8v* bp = fP + (size_t)(tb * 4) * 320 + lane;
#pragma unroll
    for (int ks = 0; ks < 5; ++ks) {
      s8v b[4];
#pragma unroll
      for (int j = 0; j < 4; ++j) b[j] = bp[j * 320 + ks * 64];
#pragma unroll
      for (int i = 0; i < 4; ++i)
#pragma unroll
        for (int j = 0; j < 4; ++j)
          acc[i][j] = __builtin_amdgcn_mfma_f32_16x16x32_bf16(a[i][ks], b[j], acc[i][j], 0, 0, 0);
    }

    __syncthreads();   // protect xs/hs from previous iteration's readers
#pragma unroll
    for (int it = 0; it < 2; ++it) {
      int idx = tid + it * 256;          // 512: 64 t x 8 i4
      int t = idx >> 3, i4 = idx & 7;
      float4 v;
      if (PASS == 1) v = *(const float4*)(xg + (size_t)(t0 + t) * 1024 + g * 32 + i4 * 4);
      else           v = *(const float4*)(xg + (size_t)g * 65536 + (size_t)(t0 + t) * 32 + i4 * 4);
      float* d = &xs[t][i4 * 4];
      d[0] = v.x; d[1] = v.y; d[2] = v.z; d[3] = v.w;
    }
    __syncthreads();

    const int tau = lane & 15, qq = lane >> 4;
#pragma unroll
    for (int tt = 0; tt < 4; ++tt) {
      int tl = tt * 16 + tau;
#pragma unroll
      for (int run = 0; run < 2; ++run) {
        float sacc = 0.f;
#pragma unroll
        for (int ch = 0; ch < 2; ++ch) {
          int ct = run * 2 + ch;
          const float* xv = &xs[tl][ch * 16 + qq * 4];
          f32x4 av = acc[ct][tt];
          sacc += av[0] * xv[0] + av[1] * xv[1] + av[2] * xv[2] + av[3] * xv[3];
        }
        sacc += __shfl_xor(sacc, 16);
        sacc += __shfl_xor(sacc, 32);
        if (lane < 16) hs[tl][w * 2 + run] = sacc;
      }
    }
    __syncthreads();

    if (tid < 128) {
      int row = tid >> 1, half = tid & 1;
      int t = t0 + row;
      int col = g * 32 + (cb & 3) * 8 + half * 4;
      float v0 = hs[row][half * 4 + 0], v1 = hs[row][half * 4 + 1];
      float v2 = hs[row][half * 4 + 2], v3 = hs[row][half * 4 + 3];
      float4 o;
      if (PASS == 2) {
        float r = rat[t];
        float4 bv = *(const float4*)(bias + (size_t)t * 1024 + col);
        o.x = fmaf(v0, r, bv.x); o.y = fmaf(v1, r, bv.y);
        o.z = fmaf(v2, r, bv.z); o.w = fmaf(v3, r, bv.w);
      } else {
        o.x = v0; o.y = v1; o.z = v2; o.w = v3;
      }
      *(float4*)(outp + (size_t)t * 1024 + col) = o;
    }
  }
}

extern "C" void kernel_launch(void* const* d_in, const int* in_sizes, int n_in,
                              void* d_out, int out_size, void* d_ws, size_t ws_size,
                              hipStream_t stream) {
  const float* x  = (const float*)d_in[0];
  const float* Wc = (const float*)d_in[1];
  const float* bc = (const float*)d_in[2];
  const float* W1 = (const float*)d_in[3];
  const float* b1 = (const float*)d_in[4];
  const float* W2 = (const float*)d_in[5];
  const float* b2 = (const float*)d_in[6];
  const float* Wm = (const float*)d_in[7];
  const float* bm = (const float*)d_in[8];
  const float* Wb = (const float*)d_in[9];
  const float* bb = (const float*)d_in[10];
  const float* Wr = (const float*)d_in[11];
  const float* br = (const float*)d_in[12];
  float* out = (float*)d_out;

  // workspace carve-up (bf16 packs first, then fp32 buffers)
  ushortT* P1 = (ushortT*)d_ws;                         // 2048*2560 bf16
  ushortT* P2 = P1 + (size_t)2048 * 2560;               // 2048*2560 bf16
  ushortT* FP = P2 + (size_t)2048 * 2560;               // 128*2560 bf16
  float* cf    = (float*)(FP + (size_t)128 * 2560);     // 2048*64
  float* ratio = cf + (size_t)NTOK * 64;                // 2048
  float* h1    = ratio + NTOK;                          // 2048*1024
  float* h1x   = h1 + (size_t)NTOK * 1024;              // 32*2048*32
  float* bias  = h1x + (size_t)NTOK * 1024;             // 2048*1024

  prep_kernel<<<dim3(256), dim3(256), 0, stream>>>(x, Wc, bc, Wm, bm, Wr, br, FP, cf, ratio);
  bias_kernel<<<dim3(256, 4), dim3(256), 0, stream>>>(cf, Wb, bb, bias);
  pack_w_kernel<<<dim3(32, 10, 2), dim3(256), 0, stream>>>(W1, b1, W2, b2, P1, P2);
  mm_kernel<1><<<dim3(1024), dim3(256), 0, stream>>>(
      (const s8v*)FP, (const s8v*)P1, x, nullptr, nullptr, h1);
  tr_kernel<<<dim3(256), dim3(256), 0, stream>>>(h1, h1x);
  mm_kernel<2><<<dim3(1024), dim3(256), 0, stream>>>(
      (const s8v*)FP, (const s8v*)P2, h1x, ratio, bias, out);
}